// Round 16
// baseline (93.456 us; speedup 1.0000x reference)
//
#include <hip/hip_runtime.h>

typedef __attribute__((ext_vector_type(8))) short bf16x8;
typedef __attribute__((ext_vector_type(4))) float f32x4;

#define XT_ROWS 4104                              // 4 pad + 4096 + 4 pad
#define XT_STRIDE ((size_t)XT_ROWS * 128)         // bytes per bdk
#define WT2_BYTES (8ull * 8 * 9 * 8192)           // 4,718,592

static __device__ __forceinline__ ushort f2bf(float f) {
    union { float f; unsigned u; } v; v.f = f;
    unsigned r = v.u + 0x7FFF + ((v.u >> 16) & 1);   // RNE
    return (ushort)(r >> 16);
}
static __device__ __forceinline__ unsigned cvtpk(float a, float b) {
    unsigned r;
    asm("v_cvt_pk_bf16_f32 %0, %1, %2" : "=v"(r) : "v"(a), "v"(b));
    return r;   // lo = bf16(a), hi = bf16(b)
}

// Merged prep (one dispatch):
//  bid < 512 : wprep — w fp32 -> wt2 swizzled bf16 image
//              (8 dk, 8 c, 9 f) x 8192 B; (o,i) at o*128+((i>>3)^(o&7))*16+(i&7)*2
//  bid >= 512: xprep — x fp32 -> xT bf16 [bdk][4104 rows][128 B], zero pad rows,
//              (row,i) at row*128 + ((i>>3)^(row&7))*16 + (i&7)*2
__global__ __launch_bounds__(256) void prep_kernel(const float* __restrict__ w,
                                                   const float* __restrict__ x,
                                                   ushort* __restrict__ wt,
                                                   ushort* __restrict__ xT) {
    __shared__ float raw[4608];
    __shared__ ushort row[72 * 64];
    __shared__ ushort XB[128 * 72];
    int bid = blockIdx.x;
    int t = threadIdx.x;
    if (bid < 512) {
        int dk = bid >> 6, o = bid & 63;
        const float* src = w + (size_t)bid * 4608;
        #pragma unroll
        for (int j = 0; j < 18; ++j) raw[t + 256 * j] = src[t + 256 * j];
        __syncthreads();
        int osw = o & 7;
        #pragma unroll
        for (int p = 0; p < 18; ++p) {
            int idx = t + 256 * p;
            int cf = idx >> 6, i = idx & 63;
            int c = cf / 9, f = cf - c * 9;
            row[cf * 64 + ((i >> 3) ^ osw) * 8 + (i & 7)] = f2bf(raw[i * 72 + c * 9 + f]);
        }
        __syncthreads();
        char* wb = (char*)wt + (size_t)dk * 8 * 9 * 8192 + o * 128;
        #pragma unroll
        for (int q = 0; q < 3; ++q) {
            int idx = q * 256 + t;
            if (idx < 576) {
                int cf = idx >> 3, cc = idx & 7;
                *(uint4*)(wb + (size_t)cf * 8192 + cc * 16) = *(const uint4*)&row[cf * 64 + cc * 8];
            }
        }
    } else {
        int bid2 = bid - 512;
        int bdk = bid2 >> 5;
        int lt  = bid2 & 31;                 // 32 tiles x 128 l
        int lq = t & 31, ig = t >> 5;        // ig 0..7 (8 i's each)
        int L0 = lt * 128;
        const float* xb = x + (size_t)bdk * 64 * 4096 + L0 + lq * 4;
        float4 v[8];
        #pragma unroll
        for (int j = 0; j < 8; ++j)
            v[j] = *(const float4*)(xb + (size_t)(ig * 8 + j) * 4096);
        #pragma unroll
        for (int k = 0; k < 4; ++k) {
            uint4 pk;
            pk.x = cvtpk(((const float*)&v[0])[k], ((const float*)&v[1])[k]);
            pk.y = cvtpk(((const float*)&v[2])[k], ((const float*)&v[3])[k]);
            pk.z = cvtpk(((const float*)&v[4])[k], ((const float*)&v[5])[k]);
            pk.w = cvtpk(((const float*)&v[6])[k], ((const float*)&v[7])[k]);
            *(uint4*)&XB[(lq * 4 + k) * 72 + ig * 8] = pk;
        }
        __syncthreads();
        char* xrb = (char*)xT + (size_t)bdk * XT_STRIDE;
        #pragma unroll
        for (int it = 0; it < 4; ++it) {
            int idx = it * 256 + t;
            int r = idx >> 3, cc = idx & 7;
            uint4 vv = *(const uint4*)&XB[r * 72 + cc * 8];
            int rowB = L0 + r + 4;
            *(uint4*)(xrb + (size_t)rowB * 128 + ((cc ^ (rowB & 7)) * 16)) = vv;
        }
        if (lt == 0 && t < 32) {
            int r = t >> 3, cc = t & 7;
            uint4 z; z.x = z.y = z.z = z.w = 0u;
            *(uint4*)(xrb + (size_t)r * 128 + ((cc ^ (r & 7)) * 16)) = z;
        }
        if (lt == 31 && t < 32) {
            int r = 4100 + (t >> 3), cc = t & 7;
            uint4 z; z.x = z.y = z.z = z.w = 0u;
            *(uint4*)(xrb + (size_t)r * 128 + ((cc ^ (r & 7)) * 16)) = z;
        }
    }
}

// conv15: LDS-FREE streaming conv. 256l x 64o tile, 512 thr, 8 waves of
// 64l x 32o. A-frags AND W-frags load straight from the swizzled global
// images into registers (double-buffered one tap ahead). Zero LDS, zero
// barriers, zero cvt, zero stage phase. xT's zero pad rows remove all
// bounds logic. Everything is L2-resident (x-tile 33KB, W 73.7KB).
__global__ __launch_bounds__(512, 4) void conv15_kernel(
    const ushort* __restrict__ xT, const ushort* __restrict__ wt,
    const float* __restrict__ bias, float* __restrict__ out)
{
    int bid = blockIdx.x;
    int b = bid / 136, rem = bid - b * 136;   // stride 136 ≡ 0 mod 8: b-sharers same XCD
    int dk = rem / 17, tile = rem - dk * 17;
    int c, lt;
    if (tile < 14) { c = tile >> 1; lt = tile & 1; } else { c = 7; lt = tile - 14; }
    int Sc = 505 * c, lb = lt << 8;
    int V = ((c == 7) ? 561 : 505) - lb; if (V > 256) V = 256;
    int bdk = b * 8 + dk;
    int R0 = Sc + lb;

    int t = threadIdx.x, lane = t & 63, wv = t >> 6;
    int ln16 = lane & 15, g = lane >> 4;
    int wr = wv >> 1, wc = wv & 1;
    int Lw = wr << 6, Ow = wc << 5;               // 64l x 32o per wave

    const char* xtb = (const char*)xT + (size_t)bdk * XT_STRIDE;
    const char* wsl = (const char*)wt + (size_t)(dk * 8 + c) * 9 * 8192;
    int qbase = R0 + Lw + ln16;                   // xT row for f=0, mf=0

    int wo[2][2];
    #pragma unroll
    for (int s = 0; s < 2; ++s)
        #pragma unroll
        for (int nf = 0; nf < 2; ++nf)
            wo[s][nf] = (Ow + nf * 16 + ln16) * 128 + (((s * 4 + g) ^ (ln16 & 7)) * 16);

    bf16x8 A0[2][4], A1[2][4], w0[2][2], w1[2][2];
    auto loadA = [&](bf16x8 (&d)[2][4], int f) {
        const char* rp = xtb + (size_t)(qbase + f) * 128;
        int k7 = (qbase + f) & 7;
        #pragma unroll
        for (int s = 0; s < 2; ++s) {
            int cof = ((s * 4 + g) ^ k7) * 16;
            #pragma unroll
            for (int mf = 0; mf < 4; ++mf)
                d[s][mf] = *(const bf16x8*)(rp + mf * 2048 + cof);
        }
    };
    auto loadW = [&](bf16x8 (&d)[2][2], int f) {
        const char* bp = wsl + (size_t)f * 8192;
        #pragma unroll
        for (int s = 0; s < 2; ++s)
            #pragma unroll
            for (int nf = 0; nf < 2; ++nf)
                d[s][nf] = *(const bf16x8*)(bp + wo[s][nf]);
    };

    f32x4 acc[4][2];
    #pragma unroll
    for (int a0 = 0; a0 < 4; ++a0)
        #pragma unroll
        for (int a1 = 0; a1 < 2; ++a1) acc[a0][a1] = (f32x4){0.f, 0.f, 0.f, 0.f};

    auto tap = [&](bf16x8 (&A)[2][4], bf16x8 (&wf)[2][2]) {
        #pragma unroll
        for (int s = 0; s < 2; ++s)
            #pragma unroll
            for (int mf = 0; mf < 4; ++mf)
                #pragma unroll
                for (int nf = 0; nf < 2; ++nf)
                    acc[mf][nf] = __builtin_amdgcn_mfma_f32_16x16x32_bf16(A[s][mf], wf[s][nf], acc[mf][nf], 0, 0, 0);
    };

    loadA(A0, 0); loadW(w0, 0);
    loadA(A1, 1); loadW(w1, 1);

    tap(A0, w0); loadA(A0, 2); loadW(w0, 2);
    tap(A1, w1); loadA(A1, 3); loadW(w1, 3);
    tap(A0, w0); loadA(A0, 4); loadW(w0, 4);
    tap(A1, w1); loadA(A1, 5); loadW(w1, 5);
    tap(A0, w0); loadA(A0, 6); loadW(w0, 6);
    tap(A1, w1); loadA(A1, 7); loadW(w1, 7);
    tap(A0, w0); loadA(A0, 8); loadW(w0, 8);
    tap(A1, w1);
    tap(A0, w0);

    // ---- epilogue: bias + direct f32x4 stores (4 lanes = 64 B contiguous) ----
    float* ob = out + ((size_t)(bdk * 64)) * 4096 + Sc + lb;
    #pragma unroll
    for (int nf = 0; nf < 2; ++nf) {
        int o = Ow + nf * 16 + ln16;
        float bvs = bias[(dk * 64 + o) * 8 + c];
        #pragma unroll
        for (int mf = 0; mf < 4; ++mf) {
            int l = Lw + mf * 16 + g * 4;
            f32x4 vv = acc[mf][nf];
            vv[0] += bvs; vv[1] += bvs; vv[2] += bvs; vv[3] += bvs;
            if (l + 4 <= V) {
                *(f32x4*)(ob + (size_t)o * 4096 + l) = vv;
            } else if (l < V) {
                #pragma unroll
                for (int r = 0; r < 4; ++r)
                    if (l + r < V) ob[(size_t)o * 4096 + l + r] = vv[r];
            }
        }
    }
}

extern "C" void kernel_launch(void* const* d_in, const int* in_sizes, int n_in,
                              void* d_out, int out_size, void* d_ws, size_t ws_size,
                              hipStream_t stream) {
    const float* x    = (const float*)d_in[0];
    const float* wgt  = (const float*)d_in[1];
    const float* bias = (const float*)d_in[2];
    float* out        = (float*)d_out;
    ushort* wt2       = (ushort*)d_ws;                       // 4,718,592 B
    ushort* xT        = (ushort*)((char*)d_ws + WT2_BYTES);  // 33,619,968 B

    hipLaunchKernelGGL(prep_kernel, dim3(2560), dim3(256), 0, stream, wgt, x, wt2, xT);
    hipLaunchKernelGGL(conv15_kernel, dim3(1088), dim3(512), 0, stream, xT, wt2, bias, out);
}

// Round 17
// 57.701 us; speedup vs baseline: 1.6197x; 1.6197x over previous
//
#include <hip/hip_runtime.h>

typedef __attribute__((ext_vector_type(8))) short bf16x8;
typedef __attribute__((ext_vector_type(4))) float f32x4;

#define WT2_BYTES (8ull * 8 * 9 * 8192)           // 4,718,592

#define AS1C(p) ((const __attribute__((address_space(1))) void*)(p))
#define AS3(p)  ((__attribute__((address_space(3))) void*)(p))

static __device__ __forceinline__ ushort f2bf(float f) {
    union { float f; unsigned u; } v; v.f = f;
    unsigned r = v.u + 0x7FFF + ((v.u >> 16) & 1);   // RNE
    return (ushort)(r >> 16);
}
static __device__ __forceinline__ unsigned cvtpk(float a, float b) {
    unsigned r;
    asm("v_cvt_pk_bf16_f32 %0, %1, %2" : "=v"(r) : "v"(a), "v"(b));
    return r;   // lo = bf16(a), hi = bf16(b)
}

// w: (8 dk, 64 o, 64 i, 8 c, 9 f) fp32
// -> wt2: (8 dk, 8 c, 9 f) slices of 8192 B; element (o,i) at byte
//    o*128 + ((i>>3) ^ (o&7))*16 + (i&7)*2   (XOR-swizzle baked in)
__global__ __launch_bounds__(256) void wprep3_kernel(const float* __restrict__ w,
                                                     ushort* __restrict__ wt) {
    __shared__ float raw[4608];
    __shared__ ushort row[72 * 64];
    int bid = blockIdx.x;
    int dk = bid >> 6, o = bid & 63;
    const float* src = w + (size_t)bid * 4608;
    int t = threadIdx.x;
    #pragma unroll
    for (int j = 0; j < 18; ++j) raw[t + 256 * j] = src[t + 256 * j];
    __syncthreads();
    int osw = o & 7;
    #pragma unroll
    for (int p = 0; p < 18; ++p) {
        int idx = t + 256 * p;
        int cf = idx >> 6, i = idx & 63;
        int c = cf / 9, f = cf - c * 9;
        row[cf * 64 + ((i >> 3) ^ osw) * 8 + (i & 7)] = f2bf(raw[i * 72 + c * 9 + f]);
    }
    __syncthreads();
    char* wb = (char*)wt + (size_t)dk * 8 * 9 * 8192 + o * 128;
    #pragma unroll
    for (int q = 0; q < 3; ++q) {
        int idx = q * 256 + t;
        if (idx < 576) {
            int cf = idx >> 3, cc = idx & 7;
            *(uint4*)(wb + (size_t)cf * 8192 + cc * 16) = *(const uint4*)&row[cf * 64 + cc * 8];
        }
    }
}

// conv17 = conv8 (128l x 64o, 4 waves, 4-deep counted-vmcnt W window) made
// PERSISTENT (grid 768, stride over 2112 tiles) with next-tile X loads issued
// in vmcnt deadline order (after W8, at the tap-5 slot -> ~3.5 taps in
// flight). Serial per-tile work collapses to cvt+ds_write. Halo loads are
// issued by ALL waves (redundant) so per-wave vmcnt counts stay uniform.
__global__ __launch_bounds__(256, 3) void conv17_kernel(
    const float* __restrict__ x, const ushort* __restrict__ wt,
    const float* __restrict__ bias, float* __restrict__ out)
{
    __shared__ __align__(16) ushort XL[136 * 64];   // 17408 B, [r][i] swizzled
    __shared__ __align__(16) ushort WL[4 * 4096];   // 32768 B, 4-tap window

    const int NT = 2112, GS = 768;
    int t = threadIdx.x, lane = t & 63, wv = t >> 6;
    int ln16 = lane & 15, g = lane >> 4;
    int wr = wv >> 1, wc = wv & 1;
    int Lw = wr << 6, Ow = wc << 5;               // 64l x 32o per wave
    int lq = t & 31, ig = t >> 5;                 // X-stage mapping
    int rh = 128 + (lane >> 3), igh = lane & 7;   // halo mapping (per wave!)

    auto dec = [&](int tid, int& bdk, int& dk, int& c, int& V, int& R0) {
        bdk = tid / 33; int tile = tid - bdk * 33;
        dk = bdk & 7;
        int lt;
        if (tile < 28) { c = tile >> 2; lt = tile & 3; } else { c = 7; lt = tile - 28; }
        int lb = lt << 7;
        V = ((c == 7) ? 561 : 505) - lb; if (V > 128) V = 128;
        R0 = 505 * c + lb;
    };

    float4 v[8]; float hv[8];
    auto xload = [&](int bdkX, int R0X) {
        const float* xb = x + (size_t)bdkX * 64 * 4096;
        bool edge = (R0X < 4) || (R0X > 3964);
        if (!edge) {
            const float* xp = xb + (size_t)ig * 8 * 4096 + (R0X - 4 + lq * 4);
            #pragma unroll
            for (int j = 0; j < 8; ++j)
                v[j] = *(const float4*)(xp + (size_t)j * 4096);
        } else {
            #pragma unroll
            for (int j = 0; j < 8; ++j) {
                float* pv = (float*)&v[j];
                #pragma unroll
                for (int k = 0; k < 4; ++k) {
                    int xr = R0X - 4 + lq * 4 + k;
                    bool ok = (xr >= 0) && (xr < 4096);
                    int xc = ok ? xr : 0;
                    pv[k] = ok ? xb[(size_t)(ig * 8 + j) * 4096 + xc] : 0.0f;
                }
            }
        }
        // halo rows 128..135: ALL waves issue (uniform vmcnt counts)
        {
            int xr = R0X - 4 + rh;                // >= 124 always
            bool okh = xr < 4096;
            int xc = okh ? xr : 0;
            const float* xh = xb + (size_t)igh * 8 * 4096 + xc;
            #pragma unroll
            for (int j = 0; j < 8; ++j) hv[j] = okh ? xh[(size_t)j * 4096] : 0.0f;
        }
    };
    auto xwrite = [&]() {
        #pragma unroll
        for (int k = 0; k < 4; ++k) {
            int r = lq * 4 + k;
            uint4 A;
            A.x = cvtpk(((const float*)&v[0])[k], ((const float*)&v[1])[k]);
            A.y = cvtpk(((const float*)&v[2])[k], ((const float*)&v[3])[k]);
            A.z = cvtpk(((const float*)&v[4])[k], ((const float*)&v[5])[k]);
            A.w = cvtpk(((const float*)&v[6])[k], ((const float*)&v[7])[k]);
            *(uint4*)((char*)XL + r * 128 + ((ig ^ (r & 7)) * 16)) = A;
        }
        {   // all waves write halo (same values, benign duplication)
            uint4 A;
            A.x = cvtpk(hv[0], hv[1]); A.y = cvtpk(hv[2], hv[3]);
            A.z = cvtpk(hv[4], hv[5]); A.w = cvtpk(hv[6], hv[7]);
            *(uint4*)((char*)XL + rh * 128 + ((igh ^ (rh & 7)) * 16)) = A;
        }
    };

    auto stageW = [&](const char* wsl, int f, int buf) {
        __builtin_amdgcn_global_load_lds(AS1C(wsl + (size_t)f * 8192 + t * 16),
                                         AS3((char*)WL + buf * 8192 + t * 16), 16, 0, 0);
        __builtin_amdgcn_global_load_lds(AS1C(wsl + (size_t)f * 8192 + 4096 + t * 16),
                                         AS3((char*)WL + buf * 8192 + 4096 + t * 16), 16, 0, 0);
    };

    f32x4 acc[4][2];
    auto tap = [&](int f) {
        int buf = f & 3;
        int rbase = Lw + ln16 + f;
        int swz = rbase & 7;
        #pragma unroll
        for (int s = 0; s < 2; ++s) {
            int cof = ((s * 4 + g) ^ swz) * 16;
            int wof = buf * 8192 + ((s * 4 + g) ^ (ln16 & 7)) * 16;
            bf16x8 av[4], bv[2];
            #pragma unroll
            for (int mf = 0; mf < 4; ++mf)
                av[mf] = *(const bf16x8*)((const char*)XL + (rbase + mf * 16) * 128 + cof);
            #pragma unroll
            for (int nf = 0; nf < 2; ++nf)
                bv[nf] = *(const bf16x8*)((const char*)WL + wof + (Ow + nf * 16 + ln16) * 128);
            #pragma unroll
            for (int mf = 0; mf < 4; ++mf)
                #pragma unroll
                for (int nf = 0; nf < 2; ++nf)
                    acc[mf][nf] = __builtin_amdgcn_mfma_f32_16x16x32_bf16(av[mf], bv[nf], acc[mf][nf], 0, 0, 0);
        }
    };
    auto epilogue = [&](int bdk, int dk, int c, int V, int R0) {
        float* ob = out + ((size_t)(bdk * 64)) * 4096 + R0;
        #pragma unroll
        for (int nf = 0; nf < 2; ++nf) {
            int o = Ow + nf * 16 + ln16;
            float bvs = bias[(dk * 64 + o) * 8 + c];
            #pragma unroll
            for (int mf = 0; mf < 4; ++mf) {
                int l = Lw + mf * 16 + g * 4;
                f32x4 vv = acc[mf][nf];
                vv[0] += bvs; vv[1] += bvs; vv[2] += bvs; vv[3] += bvs;
                if (l + 4 <= V) {
                    *(f32x4*)(ob + (size_t)o * 4096 + l) = vv;
                } else if (l < V) {
                    #pragma unroll
                    for (int r = 0; r < 4; ++r)
                        if (l + r < V) ob[(size_t)o * 4096 + l + r] = vv[r];
                }
            }
        }
    };

#define TS(Nstr) \
    asm volatile("s_waitcnt vmcnt(" Nstr ") lgkmcnt(0)" ::: "memory"); \
    __builtin_amdgcn_s_barrier(); \
    __builtin_amdgcn_sched_barrier(0);

    int tid = blockIdx.x;
    int bdk, dk, c, V, R0;
    dec(tid, bdk, dk, c, V, R0);
    xload(bdk, R0);        // prologue: serial first stage (once per block)
    xwrite();

    while (true) {
        const char* wsl = (const char*)wt + (size_t)(dk * 8 + c) * 9 * 8192;
        bool pf = (tid + GS) < NT;
        int bdkN = 0, dkN = 0, cN = 0, VN = 0, R0N = 0;
        if (pf) dec(tid + GS, bdkN, dkN, cN, VN, R0N);

        stageW(wsl, 0, 0); stageW(wsl, 1, 1); stageW(wsl, 2, 2);

        #pragma unroll
        for (int a0 = 0; a0 < 4; ++a0)
            #pragma unroll
            for (int a1 = 0; a1 < 2; ++a1) acc[a0][a1] = (f32x4){0.f, 0.f, 0.f, 0.f};

        if (pf) {
            // vmcnt deadlines in issue order: W0..W8 then x16 (consumed after tap8)
            TS("4")  stageW(wsl, 3, 3); tap(0);
            TS("4")  stageW(wsl, 4, 0); tap(1);
            TS("4")  stageW(wsl, 5, 1); tap(2);
            TS("4")  stageW(wsl, 6, 2); tap(3);
            TS("4")  stageW(wsl, 7, 3); tap(4);
            TS("4")  stageW(wsl, 8, 0); xload(bdkN, R0N); tap(5);
            TS("20") tap(6);                       // W6 done: W7,W8,x16 younger
            TS("18") tap(7);                       // W7 done: W8,x16
            TS("16") tap(8);                       // W8 done: x16 still in flight
        } else {
            TS("4")  stageW(wsl, 3, 3); tap(0);
            TS("4")  stageW(wsl, 4, 0); tap(1);
            TS("4")  stageW(wsl, 5, 1); tap(2);
            TS("4")  stageW(wsl, 6, 2); tap(3);
            TS("4")  stageW(wsl, 7, 3); tap(4);
            TS("4")  stageW(wsl, 8, 0); tap(5);
            TS("4")  tap(6);
            TS("2")  tap(7);
            TS("0")  tap(8);
        }

        epilogue(bdk, dk, c, V, R0);
        if (!pf) break;
        __syncthreads();       // all waves done reading XL/WL (drains x loads too)
        xwrite();              // stage next tile into XL (visible after tap0 barrier)
        tid += GS; bdk = bdkN; dk = dkN; c = cN; V = VN; R0 = R0N;
    }
#undef TS
}

extern "C" void kernel_launch(void* const* d_in, const int* in_sizes, int n_in,
                              void* d_out, int out_size, void* d_ws, size_t ws_size,
                              hipStream_t stream) {
    const float* x    = (const float*)d_in[0];
    const float* wgt  = (const float*)d_in[1];
    const float* bias = (const float*)d_in[2];
    float* out        = (float*)d_out;
    ushort* wt2       = (ushort*)d_ws;            // 4,718,592 B

    hipLaunchKernelGGL(wprep3_kernel, dim3(512), dim3(256), 0, stream, wgt, wt2);
    hipLaunchKernelGGL(conv17_kernel, dim3(768), dim3(256), 0, stream, x, wt2, bias, out);
}